// Round 1
// baseline (442.268 us; speedup 1.0000x reference)
//
#include <hip/hip_runtime.h>

typedef unsigned short u16;
typedef unsigned int   u32;

constexpr int N = 50000;   // nodes
constexpr int E = 600000;  // edges
constexpr int D = 128;     // feature dim
constexpr int S = 128;     // adjacency slots per node (deg ~ Poisson(24); P(deg>128) ~ 1e-44)

typedef __attribute__((ext_vector_type(8))) short s16x8;
typedef __attribute__((ext_vector_type(4))) float f32x4;

__device__ __forceinline__ u16 f2bf(float f) {
    u32 u = __builtin_bit_cast(u32, f);
    u32 r = (u + 0x7fffu + ((u >> 16) & 1u)) >> 16;  // RNE
    return (u16)r;
}
__device__ __forceinline__ float bflo(u32 v) { return __builtin_bit_cast(float, v << 16); }
__device__ __forceinline__ float bfhi(u32 v) { return __builtin_bit_cast(float, v & 0xffff0000u); }

// ---------------------------------------------------------------- adjacency
__global__ __launch_bounds__(256) void build_adj(const int2* __restrict__ edges,
                                                 int* __restrict__ cnt,
                                                 u16* __restrict__ adj) {
    int e = blockIdx.x * 256 + threadIdx.x;
    if (e >= E) return;
    int2 sd = edges[e];
    int ps = atomicAdd(&cnt[sd.x], 1);
    if (ps < S) adj[(size_t)sd.x * S + ps] = (u16)sd.y;
    int pd = atomicAdd(&cnt[sd.y], 1);
    if (pd < S) adj[(size_t)sd.y * S + pd] = (u16)sd.x;
}

// ---------------------------------------------------------------- fp32 -> bf16
__global__ __launch_bounds__(256) void cvt4(const float4* __restrict__ in,
                                            ushort4* __restrict__ out, int n4) {
    int i = blockIdx.x * 256 + threadIdx.x;
    if (i >= n4) return;
    float4 v = in[i];
    ushort4 o;
    o.x = f2bf(v.x); o.y = f2bf(v.y); o.z = f2bf(v.z); o.w = f2bf(v.w);
    out[i] = o;
}

// ---------------------------------------------------------------- GEMM: h = X@W1^T (y=0), p = X@W0^T (y=1)
// block tile 64 rows x 128 cols; 4 waves (2x2); wave tile 32x64; MFMA 16x16x32 bf16
constexpr int LDSK = 136;  // padded element stride (k-dim) to break LDS bank aliasing

__global__ __launch_bounds__(256) void gemm_xw(const u16* __restrict__ xb,
                                               const u16* __restrict__ Wb1,
                                               const u16* __restrict__ Wb0,
                                               u16* __restrict__ hout,
                                               u16* __restrict__ pout) {
    __shared__ u16 Xs[64 * LDSK];
    __shared__ u16 Ws[128 * LDSK];
    const int tid  = threadIdx.x;
    const int row0 = blockIdx.x * 64;
    const u16* W = blockIdx.y ? Wb0 : Wb1;
    u16* out     = blockIdx.y ? pout : hout;

    // stage X tile (64x128 bf16): 1024 chunks of 8 elems, 4 per thread
    #pragma unroll
    for (int it = 0; it < 4; ++it) {
        int chunk = tid + it * 256;
        int r = chunk >> 4, c8 = (chunk & 15) * 8;
        int gr = row0 + r;
        uint4 v = make_uint4(0u, 0u, 0u, 0u);
        if (gr < N) v = *(const uint4*)(xb + (size_t)gr * D + c8);
        *(uint4*)(&Xs[r * LDSK + c8]) = v;
    }
    // stage whole W half (128x128 bf16)
    #pragma unroll
    for (int it = 0; it < 8; ++it) {
        int chunk = tid + it * 256;
        int r = chunk >> 4, c8 = (chunk & 15) * 8;
        *(uint4*)(&Ws[r * LDSK + c8]) = *(const uint4*)(W + r * D + c8);
    }
    __syncthreads();

    const int wave = tid >> 6, lane = tid & 63;
    const int wm = (wave >> 1) * 32;   // wave row offset in block tile
    const int wn = (wave & 1) * 64;    // wave col offset
    const int lr = lane & 15;          // fragment m/n index
    const int lk = (lane >> 4) * 8;    // fragment k base

    f32x4 acc[2][4] = {};
    #pragma unroll
    for (int kc = 0; kc < 4; ++kc) {
        int kb = kc * 32 + lk;
        s16x8 a0 = *(const s16x8*)(&Xs[(wm      + lr) * LDSK + kb]);
        s16x8 a1 = *(const s16x8*)(&Xs[(wm + 16 + lr) * LDSK + kb]);
        #pragma unroll
        for (int nt = 0; nt < 4; ++nt) {
            s16x8 b = *(const s16x8*)(&Ws[(wn + nt * 16 + lr) * LDSK + kb]);
            acc[0][nt] = __builtin_amdgcn_mfma_f32_16x16x32_bf16(a0, b, acc[0][nt], 0, 0, 0);
            acc[1][nt] = __builtin_amdgcn_mfma_f32_16x16x32_bf16(a1, b, acc[1][nt], 0, 0, 0);
        }
    }

    const int quad = lane >> 4;
    #pragma unroll
    for (int mt = 0; mt < 2; ++mt) {
        int rbase = row0 + wm + mt * 16 + quad * 4;
        #pragma unroll
        for (int nt = 0; nt < 4; ++nt) {
            int gcol = wn + nt * 16 + lr;
            #pragma unroll
            for (int r = 0; r < 4; ++r) {
                int grow = rbase + r;
                if (grow < N) out[(size_t)grow * D + gcol] = f2bf(acc[mt][nt][r]);
            }
        }
    }
}

// ---------------------------------------------------------------- gather + combine
// wave per node (64 lanes x 2 features), 4 nodes per block
// mode 0: f = p + b + agg/deg                (first layer, write bf16 xnext)
// mode 1: f = relu(p + b + agg/deg)          (mid layers, write bf16 xnext)
// mode 2: f = relu(p + b + agg/deg + res)    (last layer, write fp32 d_out)
__global__ __launch_bounds__(256) void gather_combine(
    const u32* __restrict__ h2, const u32* __restrict__ p2,
    const int* __restrict__ cnt, const u16* __restrict__ adj,
    const float* __restrict__ bias, const float* __restrict__ res,
    u32* __restrict__ xnext, float* __restrict__ fout, int mode)
{
    __shared__ u16 snbr[4 * S];
    const int tid  = threadIdx.x;
    const int slot = tid >> 6;
    const int lane = tid & 63;
    const int node = blockIdx.x * 4 + slot;   // N divisible by 4

    int deg = cnt[node];
    int dclamp = deg > S ? S : deg;
    for (int b = lane; b < dclamp; b += 64)
        snbr[slot * S + b] = adj[(size_t)node * S + b];
    __syncthreads();

    float ax = 0.f, ay = 0.f;
    const int base = slot * S;
    int e = 0;
    for (; e + 2 <= dclamp; e += 2) {
        int n0 = snbr[base + e];
        int n1 = snbr[base + e + 1];
        u32 v0 = h2[(size_t)n0 * 64 + lane];
        u32 v1 = h2[(size_t)n1 * 64 + lane];
        ax += bflo(v0) + bflo(v1);
        ay += bfhi(v0) + bfhi(v1);
    }
    if (e < dclamp) {
        u32 v0 = h2[(size_t)snbr[base + e] * 64 + lane];
        ax += bflo(v0); ay += bfhi(v0);
    }

    float fdeg = deg > 0 ? (float)deg : 1.0f;
    u32 pv = p2[(size_t)node * 64 + lane];
    float2 bv = *(const float2*)(bias + lane * 2);
    float gx = bflo(pv) + bv.x + ax / fdeg;
    float gy = bfhi(pv) + bv.y + ay / fdeg;
    if (mode == 2) {
        float2 rv = *(const float2*)(res + (size_t)node * D + lane * 2);
        gx = fmaxf(gx + rv.x, 0.f);
        gy = fmaxf(gy + rv.y, 0.f);
        float2 o; o.x = gx; o.y = gy;
        *(float2*)(fout + (size_t)node * D + lane * 2) = o;
    } else {
        if (mode == 1) { gx = fmaxf(gx, 0.f); gy = fmaxf(gy, 0.f); }
        xnext[(size_t)node * 64 + lane] = (u32)f2bf(gx) | ((u32)f2bf(gy) << 16);
    }
}

// ---------------------------------------------------------------- launch
extern "C" void kernel_launch(void* const* d_in, const int* in_sizes, int n_in,
                              void* d_out, int out_size, void* d_ws, size_t ws_size,
                              hipStream_t stream)
{
    (void)in_sizes; (void)n_in; (void)out_size; (void)ws_size;
    const float* features = (const float*)d_in[0];
    const int*   edges    = (const int*)d_in[1];
    // d_in[2] = dis — unused by the reference
    const float* W0f = (const float*)d_in[3];
    const float* W1f = (const float*)d_in[4];
    const float* b_first = (const float*)d_in[5];
    const float* W0h = (const float*)d_in[6];
    const float* W1h = (const float*)d_in[7];
    const float* b_h = (const float*)d_in[8];
    float* out = (float*)d_out;

    char* ws = (char*)d_ws;
    size_t off = 0;
    auto alloc = [&](size_t bytes) -> void* {
        void* ptr = ws + off;
        off += (bytes + 255) & ~(size_t)255;
        return ptr;
    };
    int* cnt = (int*)alloc((size_t)N * 4);
    u16* adj = (u16*)alloc((size_t)N * S * 2);
    u16* xb0 = (u16*)alloc((size_t)N * D * 2);
    u16* xb1 = (u16*)alloc((size_t)N * D * 2);
    u16* hb  = (u16*)alloc((size_t)N * D * 2);
    u16* pb  = (u16*)alloc((size_t)N * D * 2);
    u16* Wb  = (u16*)alloc((size_t)8 * D * D * 2);

    u16* Wb_W1f = Wb;
    u16* Wb_W0f = Wb + D * D;
    u16* Wb_W1h = Wb + 2 * D * D;   // 3 mats contiguous
    u16* Wb_W0h = Wb + 5 * D * D;   // 3 mats contiguous

    hipMemsetAsync(cnt, 0, (size_t)N * 4, stream);
    build_adj<<<(E + 255) / 256, 256, 0, stream>>>((const int2*)edges, cnt, adj);

    cvt4<<<(N * D / 4 + 255) / 256, 256, 0, stream>>>((const float4*)features, (ushort4*)xb0, N * D / 4);
    cvt4<<<(D * D / 4 + 255) / 256, 256, 0, stream>>>((const float4*)W1f, (ushort4*)Wb_W1f, D * D / 4);
    cvt4<<<(D * D / 4 + 255) / 256, 256, 0, stream>>>((const float4*)W0f, (ushort4*)Wb_W0f, D * D / 4);
    cvt4<<<(3 * D * D / 4 + 255) / 256, 256, 0, stream>>>((const float4*)W1h, (ushort4*)Wb_W1h, 3 * D * D / 4);
    cvt4<<<(3 * D * D / 4 + 255) / 256, 256, 0, stream>>>((const float4*)W0h, (ushort4*)Wb_W0h, 3 * D * D / 4);

    dim3 ggrid((N + 63) / 64, 2);
    u16* xcur = xb0;
    u16* xping[2] = { xb1, xb0 };
    for (int l = 0; l < 4; ++l) {
        const u16* w1 = (l == 0) ? Wb_W1f : Wb_W1h + (l - 1) * D * D;
        const u16* w0 = (l == 0) ? Wb_W0f : Wb_W0h + (l - 1) * D * D;
        const float* bias = (l == 0) ? b_first : b_h + (l - 1) * D;
        gemm_xw<<<ggrid, 256, 0, stream>>>(xcur, w1, w0, hb, pb);
        int mode = (l == 0) ? 0 : (l == 3 ? 2 : 1);
        u16* xnext = xping[l & 1];
        gather_combine<<<N / 4, 256, 0, stream>>>((const u32*)hb, (const u32*)pb, cnt, adj,
                                                  bias, features, (u32*)xnext, out, mode);
        xcur = xnext;
    }
}